// Round 3
// baseline (3115.447 us; speedup 1.0000x reference)
//
#include <hip/hip_runtime.h>
#include <float.h>

#define S_  4096
#define B_  8
#define D_  768
#define H_  12
#define HD_ 64
#define W_  128
#define NW_ 32
#define JW_ 384
#define BH_ 96
#define SB_ 32768
#define QKV_ELEMS 25165824ull   // BH_*S_*HD_

// ---------------- mask format sniffing ----------------
// bool mask may arrive as int32 words (0/1) or packed bytes. Detect once.
__device__ __forceinline__ bool mask_at(const void* mp, int flag, int idx){
  return flag ? (((const unsigned char*)mp)[idx] != 0)
              : (((const unsigned int*)mp)[idx] != 0u);
}

__global__ __launch_bounds__(256) void sniff_mask_kernel(const unsigned int* __restrict__ m,
                                                         int* __restrict__ flag){
  __shared__ unsigned int red[256];
  unsigned int acc = 0u;
  for (int i = threadIdx.x; i < 8192; i += 256) acc |= m[i];  // 32KB: safe for both layouts
  red[threadIdx.x] = acc;
  __syncthreads();
  for (int s = 128; s > 0; s >>= 1){
    if ((int)threadIdx.x < s) red[threadIdx.x] |= red[threadIdx.x + s];
    __syncthreads();
  }
  if (threadIdx.x == 0){
    unsigned int o = red[0];
    // int32 0/1 -> o<=1. packed bytes 0/1 -> o>1 but no bits above bit0 of any byte.
    // f32 1.0f (0x3F800000) would set 0xFE-masked bits -> word mode.
    *flag = (o > 1u && (o & 0xFEFEFEFEu) == 0u) ? 1 : 0;
  }
}

// ---------------- projection GEMM: C = hid @ W + b, scattered to (b*H+h, s, hd) ----------------
__global__ __launch_bounds__(256) void proj_gemm_kernel(
    const float* __restrict__ hid, const float* __restrict__ Wm,
    const float* __restrict__ bias, float* __restrict__ dst){
  __shared__ float As[16][132];   // [k][m] transposed A tile (128 rows)
  __shared__ float Bs[16][136];   // [k][n] B tile (128 cols)
  const int tx = threadIdx.x, ty = threadIdx.y;   // 16x16
  const int t  = ty * 16 + tx;
  const int r0 = blockIdx.x * 128, c0 = blockIdx.y * 128;

  float acc[8][8];
#pragma unroll
  for (int i = 0; i < 8; ++i)
#pragma unroll
    for (int j = 0; j < 8; ++j) acc[i][j] = 0.f;

  const int ar = t >> 1, akq = (t & 1) * 8;   // A: 128 rows x 16 k
  const int wk = t >> 4, wc = (t & 15) * 8;   // B: 16 k x 128 cols

  for (int k0 = 0; k0 < D_; k0 += 16){
    float4 a0 = *(const float4*)&hid[(size_t)(r0 + ar) * D_ + k0 + akq];
    float4 a1 = *(const float4*)&hid[(size_t)(r0 + ar) * D_ + k0 + akq + 4];
    float4 w0 = *(const float4*)&Wm[(size_t)(k0 + wk) * D_ + c0 + wc];
    float4 w1 = *(const float4*)&Wm[(size_t)(k0 + wk) * D_ + c0 + wc + 4];
    As[akq+0][ar] = a0.x; As[akq+1][ar] = a0.y; As[akq+2][ar] = a0.z; As[akq+3][ar] = a0.w;
    As[akq+4][ar] = a1.x; As[akq+5][ar] = a1.y; As[akq+6][ar] = a1.z; As[akq+7][ar] = a1.w;
    *(float4*)&Bs[wk][wc]     = w0;
    *(float4*)&Bs[wk][wc + 4] = w1;
    __syncthreads();
#pragma unroll
    for (int kk = 0; kk < 16; ++kk){
      float4 af0 = *(const float4*)&As[kk][ty * 4];
      float4 af1 = *(const float4*)&As[kk][64 + ty * 4];
      float4 bf0 = *(const float4*)&Bs[kk][tx * 4];
      float4 bf1 = *(const float4*)&Bs[kk][64 + tx * 4];
      float a[8] = {af0.x,af0.y,af0.z,af0.w, af1.x,af1.y,af1.z,af1.w};
      float b[8] = {bf0.x,bf0.y,bf0.z,bf0.w, bf1.x,bf1.y,bf1.z,bf1.w};
#pragma unroll
      for (int i = 0; i < 8; ++i)
#pragma unroll
        for (int j = 0; j < 8; ++j) acc[i][j] += a[i] * b[j];
    }
    __syncthreads();
  }

  float4 bias0 = *(const float4*)&bias[c0 + tx * 4];
  float4 bias1 = *(const float4*)&bias[c0 + 64 + tx * 4];
  float bb[8] = {bias0.x,bias0.y,bias0.z,bias0.w, bias1.x,bias1.y,bias1.z,bias1.w};

#pragma unroll
  for (int i = 0; i < 8; ++i){
    const int rloc = (i < 4) ? (ty * 4 + i) : (64 + ty * 4 + (i - 4));
    const int r = r0 + rloc;
    const int srow = r >> 3, b_i = r & 7;     // r = s*B + b
#pragma unroll
    for (int half = 0; half < 2; ++half){
      const int cb = c0 + half * 64 + tx * 4;
      const int hh = cb >> 6;
      const int d  = cb & 63;                  // = tx*4
      float4 o;
      o.x = acc[i][half*4+0] + bb[half*4+0];
      o.y = acc[i][half*4+1] + bb[half*4+1];
      o.z = acc[i][half*4+2] + bb[half*4+2];
      o.w = acc[i][half*4+3] + bb[half*4+3];
      *(float4*)&dst[((size_t)(b_i * H_ + hh) * S_ + srow) * HD_ + d] = o;
    }
  }
}

// ---------------- local windowed attention ----------------
// block: (window n_i, 32-row chunk, bh). 256 threads.
__global__ __launch_bounds__(256) void local_attn_kernel(
    const float* __restrict__ q, const float* __restrict__ k, const float* __restrict__ v,
    const void* __restrict__ maskp, const int* __restrict__ flagp,
    float* __restrict__ out){
  __shared__ float qs[32][68];
  __shared__ float kvt[64][72];     // dots phase: [d][jj] ; PV phase: [jj][dd]
  __shared__ float dotsS[32][385];
  __shared__ float kmv[JW_];
  __shared__ int   qm[32];

  const int t = threadIdx.x;
  const int bh = blockIdx.z, b_i = bh / H_, h = bh % H_;
  const int n_i = blockIdx.x, chunk = blockIdx.y;
  const int qrow0 = n_i * W_ + chunk * 32;
  const int flag = *flagp;

  { const int i = t >> 3, d0 = (t & 7) * 8;
    const float* qp = &q[((size_t)bh * S_ + qrow0 + i) * HD_ + d0];
    float4 a = *(const float4*)qp, b = *(const float4*)(qp + 4);
    *(float4*)&qs[i][d0]     = a;
    *(float4*)&qs[i][d0 + 4] = b; }
  if (t < 32) qm[t] = mask_at(maskp, flag, b_i * S_ + qrow0 + t) ? 1 : 0;
  for (int j = t; j < JW_; j += 256){
    const int jpos = n_i * W_ - W_ + j;
    kmv[j] = (jpos < 0 || jpos >= S_) ? 1.f
           : (mask_at(maskp, flag, b_i * S_ + jpos) ? 1.f : 0.f);
  }
  __syncthreads();

  const int i_ = t >> 3;        // 0..31
  const int g8 = (t & 7) * 8;   // 0..56

  // ---- dots = q @ k^T * 1/8, masked -> -FLT_MAX ----
  for (int jt = 0; jt < 6; ++jt){
    const int jbase = n_i * W_ - W_ + jt * 64;
#pragma unroll
    for (int pass = 0; pass < 4; ++pass){
      const int jr = pass * 16 + (t >> 4), d0 = (t & 15) * 4;
      const int jpos = jbase + jr;
      float4 kv4 = make_float4(0.f, 0.f, 0.f, 0.f);
      if (jpos >= 0 && jpos < S_)
        kv4 = *(const float4*)&k[((size_t)bh * S_ + jpos) * HD_ + d0];
      kvt[d0+0][jr] = kv4.x; kvt[d0+1][jr] = kv4.y;
      kvt[d0+2][jr] = kv4.z; kvt[d0+3][jr] = kv4.w;
    }
    __syncthreads();
    float acc[8] = {0,0,0,0,0,0,0,0};
#pragma unroll 8
    for (int d = 0; d < 64; ++d){
      const float qv = qs[i_][d];
      float4 k0 = *(const float4*)&kvt[d][g8];
      float4 k1 = *(const float4*)&kvt[d][g8 + 4];
      acc[0] += qv * k0.x; acc[1] += qv * k0.y; acc[2] += qv * k0.z; acc[3] += qv * k0.w;
      acc[4] += qv * k1.x; acc[5] += qv * k1.y; acc[6] += qv * k1.z; acc[7] += qv * k1.w;
    }
    const bool qmk = qm[i_] != 0;
#pragma unroll
    for (int u = 0; u < 8; ++u){
      const int jg = jt * 64 + g8 + u;
      dotsS[i_][jg] = (qmk || kmv[jg] != 0.f) ? -FLT_MAX : acc[u] * 0.125f;
    }
    __syncthreads();
  }

  // ---- safe softmax per row (all -FLT_MAX row -> uniform, matches jax) ----
  { const int r = t >> 3, c0 = t & 7;
    float m = -FLT_MAX;
    for (int c = c0; c < JW_; c += 8) m = fmaxf(m, dotsS[r][c]);
    m = fmaxf(m, __shfl_xor(m, 1)); m = fmaxf(m, __shfl_xor(m, 2)); m = fmaxf(m, __shfl_xor(m, 4));
    float s = 0.f;
    for (int c = c0; c < JW_; c += 8){ float p = __expf(dotsS[r][c] - m); dotsS[r][c] = p; s += p; }
    s += __shfl_xor(s, 1); s += __shfl_xor(s, 2); s += __shfl_xor(s, 4);
    const float inv = 1.f / s;
    for (int c = c0; c < JW_; c += 8) dotsS[r][c] *= inv;
  }
  __syncthreads();

  // ---- out = attn @ v (zero pads outside [0,S)) ----
  float acco[8] = {0,0,0,0,0,0,0,0};
  for (int jt = 0; jt < 6; ++jt){
    const int jbase = n_i * W_ - W_ + jt * 64;
#pragma unroll
    for (int pass = 0; pass < 2; ++pass){
      const int jr = pass * 32 + (t >> 3), d0 = (t & 7) * 8;
      const int jpos = jbase + jr;
      float4 a = make_float4(0.f,0.f,0.f,0.f), b = make_float4(0.f,0.f,0.f,0.f);
      if (jpos >= 0 && jpos < S_){
        const float* vp = &v[((size_t)bh * S_ + jpos) * HD_ + d0];
        a = *(const float4*)vp; b = *(const float4*)(vp + 4);
      }
      *(float4*)&kvt[jr][d0]     = a;
      *(float4*)&kvt[jr][d0 + 4] = b;
    }
    __syncthreads();
#pragma unroll 8
    for (int jj = 0; jj < 64; ++jj){
      const float a = dotsS[i_][jt * 64 + jj];
      float4 v0 = *(const float4*)&kvt[jj][g8];
      float4 v1 = *(const float4*)&kvt[jj][g8 + 4];
      acco[0] += a * v0.x; acco[1] += a * v0.y; acco[2] += a * v0.z; acco[3] += a * v0.w;
      acco[4] += a * v1.x; acco[5] += a * v1.y; acco[6] += a * v1.z; acco[7] += a * v1.w;
    }
    __syncthreads();
  }
  { float4 o0 = make_float4(acco[0],acco[1],acco[2],acco[3]);
    float4 o1 = make_float4(acco[4],acco[5],acco[6],acco[7]);
    float* op = &out[((size_t)(qrow0 + i_) * B_ + b_i) * D_ + h * HD_ + g8];
    *(float4*)op       = o0;
    *(float4*)(op + 4) = o1; }
}

// ---------------- global token-0 attention (overwrites output row 0) ----------------
__global__ __launch_bounds__(256) void global_attn_kernel(
    const float* __restrict__ hid, const float* __restrict__ Wgq, const float* __restrict__ bgq,
    const float* __restrict__ k, const float* __restrict__ v,
    const void* __restrict__ maskp, const int* __restrict__ flagp,
    float* __restrict__ out){
  __shared__ float hs[D_];
  __shared__ float gqs[64];
  __shared__ float sc[S_];
  __shared__ float kt[256][65];
  __shared__ float red[256];
  const int t = threadIdx.x, bh = blockIdx.x, b_i = bh / H_, h = bh % H_;
  const int flag = *flagp;

  for (int c = t; c < D_; c += 256) hs[c] = hid[(size_t)b_i * D_ + c];  // hidden[0, b, :]
  __syncthreads();
  { const int dd = t & 63, part = t >> 6;
    float acc = 0.f;
    for (int c = part * 192; c < part * 192 + 192; ++c)
      acc += hs[c] * Wgq[(size_t)c * D_ + h * HD_ + dd];
    red[t] = acc; }
  __syncthreads();
  if (t < 64)
    gqs[t] = (red[t] + red[t+64] + red[t+128] + red[t+192] + bgq[h * HD_ + t]) * 0.125f;
  __syncthreads();

  for (int tile = 0; tile < 16; ++tile){
#pragma unroll
    for (int pass = 0; pass < 16; ++pass){
      const int rr = pass * 16 + (t >> 4), d0 = (t & 15) * 4;
      float4 kv4 = *(const float4*)&k[((size_t)bh * S_ + tile * 256 + rr) * HD_ + d0];
      kt[rr][d0+0] = kv4.x; kt[rr][d0+1] = kv4.y; kt[rr][d0+2] = kv4.z; kt[rr][d0+3] = kv4.w;
    }
    __syncthreads();
    float dot = 0.f;
#pragma unroll 16
    for (int d = 0; d < 64; ++d) dot += gqs[d] * kt[t][d];
    const int ss = tile * 256 + t;
    sc[ss] = mask_at(maskp, flag, b_i * S_ + ss) ? -FLT_MAX : dot;
    __syncthreads();
  }

  float m = -FLT_MAX;
  for (int ssi = t; ssi < S_; ssi += 256) m = fmaxf(m, sc[ssi]);
  red[t] = m; __syncthreads();
  for (int st = 128; st > 0; st >>= 1){ if (t < st) red[t] = fmaxf(red[t], red[t + st]); __syncthreads(); }
  m = red[0]; __syncthreads();
  float ls = 0.f;
  for (int ssi = t; ssi < S_; ssi += 256){ float p = __expf(sc[ssi] - m); sc[ssi] = p; ls += p; }
  red[t] = ls; __syncthreads();
  for (int st = 128; st > 0; st >>= 1){ if (t < st) red[t] += red[t + st]; __syncthreads(); }
  const float invs = 1.f / red[0];
  __syncthreads();

  { const int dd = t & 63, part = t >> 6;
    float acc = 0.f;
    for (int ssv = part; ssv < S_; ssv += 4)
      acc += sc[ssv] * v[((size_t)bh * S_ + ssv) * HD_ + dd];
    red[t] = acc; }
  __syncthreads();
  if (t < 64)
    out[(size_t)b_i * D_ + h * HD_ + t] =
        (red[t] + red[t+64] + red[t+128] + red[t+192]) * invs;
}

// ---------------- launch ----------------
extern "C" void kernel_launch(void* const* d_in, const int* in_sizes, int n_in,
                              void* d_out, int out_size, void* d_ws, size_t ws_size,
                              hipStream_t stream) {
  const float* hid   = (const float*)d_in[0];
  const void*  maskp = d_in[1];
  const float* Wq  = (const float*)d_in[2];
  const float* Wk  = (const float*)d_in[3];
  const float* Wv  = (const float*)d_in[4];
  const float* Wgq = (const float*)d_in[5];
  const float* bq  = (const float*)d_in[6];
  const float* bk  = (const float*)d_in[7];
  const float* bv  = (const float*)d_in[8];
  const float* bgq = (const float*)d_in[9];
  float* out = (float*)d_out;

  // flag lives at the FRONT of the workspace (always-safe small access);
  // the big q/k/v arrays follow at a 256B offset.
  int* flag = (int*)d_ws;
  float* q = (float*)((char*)d_ws + 256);
  float* k = q + QKV_ELEMS;
  float* v = k + QKV_ELEMS;

  sniff_mask_kernel<<<1, 256, 0, stream>>>((const unsigned int*)maskp, flag);

  dim3 gb(SB_ / 128, D_ / 128, 1);
  dim3 tb(16, 16, 1);
  proj_gemm_kernel<<<gb, tb, 0, stream>>>(hid, Wq, bq, q);
  proj_gemm_kernel<<<gb, tb, 0, stream>>>(hid, Wk, bk, k);
  proj_gemm_kernel<<<gb, tb, 0, stream>>>(hid, Wv, bv, v);

  dim3 ga(NW_, 4, BH_);
  local_attn_kernel<<<ga, 256, 0, stream>>>(q, k, v, maskp, flag, out);

  global_attn_kernel<<<BH_, 256, 0, stream>>>(hid, Wgq, bgq, k, v, maskp, flag, out);
}

// Round 4
// 431.212 us; speedup vs baseline: 7.2249x; 7.2249x over previous
//
#include <hip/hip_runtime.h>
#include <float.h>

#define S_  4096
#define B_  8
#define D_  768
#define H_  12
#define HD_ 64
#define W_  128
#define BH_ 96
#define SB_ 32768

typedef unsigned short u16;
// MFMA frag types (guide §3: 8 bf16 = 4 VGPRs; 4 f32 acc)
typedef __attribute__((ext_vector_type(8))) short bf16x8;
typedef __attribute__((ext_vector_type(4))) float f32x4;

#define MFMA16(a,b,c) __builtin_amdgcn_mfma_f32_16x16x32_bf16(a,b,c,0,0,0)

// f32 -> bf16 round-to-nearest-even
__device__ __forceinline__ u16 f2bf(float x){
  unsigned int u = __float_as_uint(x);
  return (u16)((u + 0x7FFFu + ((u >> 16) & 1u)) >> 16);
}
__device__ __forceinline__ float bf2f(unsigned int lo16){ return __uint_as_float(lo16 << 16); }
__device__ __forceinline__ float bflo(unsigned int u){ return __uint_as_float(u << 16); }
__device__ __forceinline__ float bfhi(unsigned int u){ return __uint_as_float(u & 0xFFFF0000u); }
__device__ __forceinline__ unsigned int pk2(float a, float b){
  return (unsigned int)f2bf(a) | ((unsigned int)f2bf(b) << 16);
}

// ---------------- mask format sniffing ----------------
__device__ __forceinline__ bool mask_at(const void* mp, int flag, int idx){
  return flag ? (((const unsigned char*)mp)[idx] != 0)
              : (((const unsigned int*)mp)[idx] != 0u);
}

__global__ __launch_bounds__(256) void sniff_mask_kernel(const unsigned int* __restrict__ m,
                                                         int* __restrict__ flag){
  __shared__ unsigned int red[256];
  unsigned int acc = 0u;
  for (int i = threadIdx.x; i < 8192; i += 256) acc |= m[i];
  red[threadIdx.x] = acc;
  __syncthreads();
  for (int s = 128; s > 0; s >>= 1){
    if ((int)threadIdx.x < s) red[threadIdx.x] |= red[threadIdx.x + s];
    __syncthreads();
  }
  if (threadIdx.x == 0){
    unsigned int o = red[0];
    *flag = (o > 1u && (o & 0xFEFEFEFEu) == 0u) ? 1 : 0;
  }
}

// ---------------- hidden f32 -> bf16 ----------------
__global__ __launch_bounds__(256) void cvt_hidden_kernel(const float* __restrict__ src,
                                                         u16* __restrict__ dst){
  int idx = blockIdx.x * 256 + threadIdx.x;
  for (int base = idx * 8; base < 25165824; base += 2048 * 256 * 8){
    float4 a = *(const float4*)&src[base];
    float4 b = *(const float4*)&src[base + 4];
    uint4 o;
    o.x = pk2(a.x, a.y); o.y = pk2(a.z, a.w);
    o.z = pk2(b.x, b.y); o.w = pk2(b.z, b.w);
    *(uint4*)&dst[base] = o;
  }
}

// ---------------- W (k-major 768x768 f32) -> WT (n-major bf16), 3 mats ----------------
__global__ __launch_bounds__(256) void cvt_wT_kernel(const float* __restrict__ W0,
    const float* __restrict__ W1, const float* __restrict__ W2, u16* __restrict__ wT){
  __shared__ float tile[64][65];
  const float* Wsel = blockIdx.z == 0 ? W0 : (blockIdx.z == 1 ? W1 : W2);
  const int t = threadIdx.x;
  const int kt0 = blockIdx.x * 64, nt0 = blockIdx.y * 64;
  { const int row = t >> 2, c16 = (t & 3) * 16;
#pragma unroll
    for (int j = 0; j < 4; ++j){
      float4 v = *(const float4*)&Wsel[(size_t)(kt0 + row) * 768 + nt0 + c16 + j * 4];
      tile[row][c16 + j*4 + 0] = v.x; tile[row][c16 + j*4 + 1] = v.y;
      tile[row][c16 + j*4 + 2] = v.z; tile[row][c16 + j*4 + 3] = v.w;
    } }
  __syncthreads();
  { const int nl = t >> 2, k16 = (t & 3) * 16;
    unsigned int o[8];
#pragma unroll
    for (int j = 0; j < 8; ++j)
      o[j] = pk2(tile[k16 + 2*j][nl], tile[k16 + 2*j + 1][nl]);
    u16* dst = wT + (size_t)blockIdx.z * 589824 + (size_t)(nt0 + nl) * 768 + kt0 + k16;
    *(uint4*)dst       = make_uint4(o[0], o[1], o[2], o[3]);
    *(uint4*)(dst + 8) = make_uint4(o[4], o[5], o[6], o[7]); }
}

// ---------------- fused 3-projection MFMA GEMM ----------------
// C(32768x768) = hb @ W + b per proj (blockIdx.y/6 selects proj), scattered to
// bf16 [bh][s][64]. 128x128 tile, BK=64, 4 waves of 64x64.
// Frag layout (gfx950 16x16x32 bf16): A/B lane holds 8 contig k at row/col=lane&15,
// k=(lane>>4)*8+j ; C/D row=(lane>>4)*4+reg, col=lane&15 (m89-verified).
__global__ __launch_bounds__(256) void proj_mfma_kernel(
    const u16* __restrict__ hb, const u16* __restrict__ wT,
    const float* __restrict__ bq, const float* __restrict__ bk, const float* __restrict__ bv,
    u16* __restrict__ qb, u16* __restrict__ kb, u16* __restrict__ vb){
  __shared__ u16 As[128][72];   // rows 144B: dword stride 36 == 4 mod 32 -> <=2-way (free)
  __shared__ u16 Bs[128][72];
  const int t = threadIdx.x;
  const int p  = blockIdx.y / 6;
  const int c0 = (blockIdx.y % 6) * 128;
  const int r0 = blockIdx.x * 128;
  const float* bias = p == 0 ? bq : (p == 1 ? bk : bv);
  u16* dst = p == 0 ? qb : (p == 1 ? kb : vb);
  const u16* wTp = wT + (size_t)p * 589824;

  const int lane = t & 63, w = t >> 6;
  const int l15 = lane & 15, lg = lane >> 4;
  const int wr = w >> 1, wc = w & 1;

  f32x4 acc[4][4] = {};

  for (int k0 = 0; k0 < 768; k0 += 64){
#pragma unroll
    for (int i = 0; i < 4; ++i){            // 1024 16B chunks per tile / 256 thr
      int chunk = i * 256 + t;
      int row = chunk >> 3, q8 = (chunk & 7) * 8;
      *(uint4*)&As[row][q8] = *(const uint4*)&hb[(size_t)(r0 + row) * 768 + k0 + q8];
      *(uint4*)&Bs[row][q8] = *(const uint4*)&wTp[(size_t)(c0 + row) * 768 + k0 + q8];
    }
    __syncthreads();
    bf16x8 af[4][2], bf[4][2];
#pragma unroll
    for (int mf = 0; mf < 4; ++mf)
#pragma unroll
      for (int ks = 0; ks < 2; ++ks)
        af[mf][ks] = *(const bf16x8*)&As[wr*64 + mf*16 + l15][ks*32 + lg*8];
#pragma unroll
    for (int nf = 0; nf < 4; ++nf)
#pragma unroll
      for (int ks = 0; ks < 2; ++ks)
        bf[nf][ks] = *(const bf16x8*)&Bs[wc*64 + nf*16 + l15][ks*32 + lg*8];
#pragma unroll
    for (int ks = 0; ks < 2; ++ks)
#pragma unroll
      for (int mf = 0; mf < 4; ++mf)
#pragma unroll
        for (int nf = 0; nf < 4; ++nf)
          acc[mf][nf] = MFMA16(af[mf][ks], bf[nf][ks], acc[mf][nf]);
    __syncthreads();
  }
#pragma unroll
  for (int nf = 0; nf < 4; ++nf){
    int c = c0 + wc*64 + nf*16 + l15;
    float bsv = bias[c];
    int hh = c >> 6, dd = c & 63;
#pragma unroll
    for (int mf = 0; mf < 4; ++mf){
      int rbase = r0 + wr*64 + mf*16 + lg*4;
#pragma unroll
      for (int r = 0; r < 4; ++r){
        int row = rbase + r;
        int s = row >> 3, b = row & 7;          // row = s*B + b
        dst[((size_t)(b * 12 + hh) * 4096 + s) * 64 + dd] = f2bf(acc[mf][nf][r] + bsv);
      }
    }
  }
}

// ---------------- v [bh][s][64] -> vt [bh][d][4096] (bf16 bit-copy transpose) ----------------
__global__ __launch_bounds__(256) void vt_kernel(const u16* __restrict__ vb, u16* __restrict__ vtb){
  __shared__ u16 tile[64][72];
  const int t = threadIdx.x;
  const int stile = blockIdx.x, bh = blockIdx.y;
  { const int sl = t >> 2, q = (t & 3) * 16;
    const u16* src = &vb[((size_t)bh * 4096 + stile * 64 + sl) * 64 + q];
    *(uint4*)&tile[sl][q]     = *(const uint4*)src;
    *(uint4*)&tile[sl][q + 8] = *(const uint4*)(src + 8); }
  __syncthreads();
  { const int d = t >> 2, sq = (t & 3) * 16;
    unsigned int o[8];
#pragma unroll
    for (int j = 0; j < 8; ++j){
      unsigned int lo = tile[sq + 2*j][d], hi = tile[sq + 2*j + 1][d];
      o[j] = lo | (hi << 16);
    }
    u16* dst = vtb + ((size_t)bh * 64 + d) * 4096 + stile * 64 + sq;
    *(uint4*)dst       = make_uint4(o[0], o[1], o[2], o[3]);
    *(uint4*)(dst + 8) = make_uint4(o[4], o[5], o[6], o[7]); }
}

// ---------------- local windowed attention, MFMA flash-style ----------------
// grid (32 windows, 96 bh), 4 waves x 32 q-rows. Per j-tile (64 ctx positions):
// stage K[j][d], Vt[d][j]; QK^T mfma; mask+scale; online softmax (f32);
// P->bf16 in per-wave LDS; PV mfma accumulates O. OOR tiles skipped; denominator
// repaired by +128 iff rowmax stayed -FLT_MAX (matches JAX uniform-384 rows).
__global__ __launch_bounds__(256) void local_mfma_kernel(
    const u16* __restrict__ qb, const u16* __restrict__ kb, const u16* __restrict__ vtb,
    const void* __restrict__ maskp, const int* __restrict__ flagp,
    float* __restrict__ out){
  __shared__ u16 Ks[64][72];
  __shared__ u16 Vs[64][72];
  __shared__ u16 Ps[4][32][72];
  __shared__ float kpen[384];
  __shared__ float qpen_s[128];
  const int t = threadIdx.x;
  const int n_i = blockIdx.x, bh = blockIdx.y;
  const int b_i = bh / 12, h = bh % 12;
  const int flag = *flagp;
  const int w = t >> 6, lane = t & 63, l15 = lane & 15, lg = lane >> 4;
  const int jbase0 = n_i * 128 - 128;

  if (t < 128) qpen_s[t] = mask_at(maskp, flag, b_i * 4096 + n_i * 128 + t) ? 1.f : 0.f;
  for (int j = t; j < 384; j += 256){
    int jp = jbase0 + j;
    kpen[j] = (jp < 0 || jp >= 4096 || mask_at(maskp, flag, b_i * 4096 + jp)) ? 1.f : 0.f;
  }
  __syncthreads();

  bf16x8 aq[2][2];
#pragma unroll
  for (int mf = 0; mf < 2; ++mf)
#pragma unroll
    for (int ks = 0; ks < 2; ++ks)
      aq[mf][ks] = *(const bf16x8*)&qb[((size_t)bh * 4096 + n_i*128 + w*32 + mf*16 + l15) * 64 + ks*32 + lg*8];

  float qp[2][4];
#pragma unroll
  for (int mf = 0; mf < 2; ++mf)
#pragma unroll
    for (int r = 0; r < 4; ++r)
      qp[mf][r] = qpen_s[w*32 + mf*16 + lg*4 + r];

  f32x4 O[2][4] = {};
  float mrow[2][4], lrow[2][4];
#pragma unroll
  for (int mf = 0; mf < 2; ++mf)
#pragma unroll
    for (int r = 0; r < 4; ++r){ mrow[mf][r] = -FLT_MAX; lrow[mf][r] = 0.f; }

  for (int jt = 0; jt < 6; ++jt){
    const int jb = jbase0 + jt * 64;
    if (jb < 0 || jb >= 4096) continue;      // block-uniform: barriers balanced
#pragma unroll
    for (int i = 0; i < 2; ++i){             // 512 chunks / 256 thr
      int chunk = i * 256 + t;
      int row = chunk >> 3, q8 = (chunk & 7) * 8;
      *(uint4*)&Ks[row][q8] = *(const uint4*)&kb[((size_t)bh * 4096 + jb + row) * 64 + q8];
      *(uint4*)&Vs[row][q8] = *(const uint4*)&vtb[((size_t)bh * 64 + row) * 4096 + jb + q8];
    }
    __syncthreads();

    f32x4 dt[2][4] = {};
#pragma unroll
    for (int ks = 0; ks < 2; ++ks)
#pragma unroll
      for (int nf = 0; nf < 4; ++nf){
        bf16x8 bk_ = *(const bf16x8*)&Ks[nf*16 + l15][ks*32 + lg*8];
        dt[0][nf] = MFMA16(aq[0][ks], bk_, dt[0][nf]);
        dt[1][nf] = MFMA16(aq[1][ks], bk_, dt[1][nf]);
      }
#pragma unroll
    for (int nf = 0; nf < 4; ++nf){
      float kp = kpen[jt*64 + nf*16 + l15];
#pragma unroll
      for (int mf = 0; mf < 2; ++mf)
#pragma unroll
        for (int r = 0; r < 4; ++r){
          float vv = dt[mf][nf][r] * 0.125f;
          dt[mf][nf][r] = (qp[mf][r] + kp == 0.f) ? vv : -FLT_MAX;
        }
    }
#pragma unroll
    for (int mf = 0; mf < 2; ++mf)
#pragma unroll
      for (int r = 0; r < 4; ++r){
        float tm = fmaxf(fmaxf(dt[mf][0][r], dt[mf][1][r]), fmaxf(dt[mf][2][r], dt[mf][3][r]));
        tm = fmaxf(tm, __shfl_xor(tm, 1));
        tm = fmaxf(tm, __shfl_xor(tm, 2));
        tm = fmaxf(tm, __shfl_xor(tm, 4));
        tm = fmaxf(tm, __shfl_xor(tm, 8));
        float mold = mrow[mf][r];
        float mnew = fmaxf(mold, tm);
        float scl = __expf(mold - mnew);     // exp(0)=1 when both -FLT_MAX
        mrow[mf][r] = mnew;
        float ps = 0.f;
#pragma unroll
        for (int nf = 0; nf < 4; ++nf){
          float pv = __expf(dt[mf][nf][r] - mnew);
          ps += pv;
          Ps[w][mf*16 + lg*4 + r][nf*16 + l15] = f2bf(pv);
          O[mf][nf][r] *= scl;
        }
        ps += __shfl_xor(ps, 1);
        ps += __shfl_xor(ps, 2);
        ps += __shfl_xor(ps, 4);
        ps += __shfl_xor(ps, 8);
        lrow[mf][r] = lrow[mf][r] * scl + ps;
      }
#pragma unroll
    for (int ks = 0; ks < 2; ++ks){
      bf16x8 ap0 = *(const bf16x8*)&Ps[w][l15]     [ks*32 + lg*8];
      bf16x8 ap1 = *(const bf16x8*)&Ps[w][16 + l15][ks*32 + lg*8];
#pragma unroll
      for (int nf = 0; nf < 4; ++nf){
        bf16x8 bv_ = *(const bf16x8*)&Vs[nf*16 + l15][ks*32 + lg*8];
        O[0][nf] = MFMA16(ap0, bv_, O[0][nf]);
        O[1][nf] = MFMA16(ap1, bv_, O[1][nf]);
      }
    }
    __syncthreads();
  }

  const float noor = (n_i == 0 || n_i == 31) ? 128.f : 0.f;
#pragma unroll
  for (int mf = 0; mf < 2; ++mf)
#pragma unroll
    for (int r = 0; r < 4; ++r){
      float lf = lrow[mf][r] + ((mrow[mf][r] <= -FLT_MAX) ? noor : 0.f);
      float inv = 1.f / lf;
      int srow = n_i*128 + w*32 + mf*16 + lg*4 + r;
      float* op = &out[(size_t)srow * (8 * 768) + b_i * 768 + h * 64];
#pragma unroll
      for (int nf = 0; nf < 4; ++nf)
        op[nf*16 + l15] = O[mf][nf][r] * inv;
    }
}

// ---------------- global token-0 attention: gq, split-S partials, combine ----------------
__global__ __launch_bounds__(256) void gq_kernel(const float* __restrict__ hid,
    const float* __restrict__ Wgq, const float* __restrict__ bgq, float* __restrict__ gq){
  __shared__ float hs[768];
  __shared__ float red[256];
  const int t = threadIdx.x, bh = blockIdx.x, b_i = bh / 12, h = bh % 12;
  for (int c = t; c < 768; c += 256) hs[c] = hid[(size_t)b_i * 768 + c];
  __syncthreads();
  const int dd = t & 63, part = t >> 6;
  float acc = 0.f;
  for (int c = part * 192; c < part * 192 + 192; ++c)
    acc += hs[c] * Wgq[(size_t)c * 768 + h * 64 + dd];
  red[t] = acc;
  __syncthreads();
  if (t < 64)
    gq[bh * 64 + t] = (red[t] + red[t+64] + red[t+128] + red[t+192] + bgq[h*64 + t]) * 0.125f;
}

__global__ __launch_bounds__(256) void gpart_kernel(const float* __restrict__ gq,
    const u16* __restrict__ kb, const u16* __restrict__ vb,
    const void* __restrict__ maskp, const int* __restrict__ flagp,
    float* __restrict__ gp_out){
  __shared__ float gqs[64];
  __shared__ float sc[512];
  __shared__ float red[256];
  const int t = threadIdx.x, bh = blockIdx.x, chunk = blockIdx.y;
  const int b_i = bh / 12;
  const int flag = *flagp;
  if (t < 64) gqs[t] = gq[bh * 64 + t];
  __syncthreads();
#pragma unroll
  for (int i = 0; i < 2; ++i){
    int sl = i * 256 + t;
    int s = chunk * 512 + sl;
    const uint4* kr = (const uint4*)&kb[((size_t)bh * 4096 + s) * 64];
    float dot = 0.f;
#pragma unroll
    for (int u = 0; u < 8; ++u){
      uint4 x = kr[u];
      dot += gqs[u*8+0]*bflo(x.x) + gqs[u*8+1]*bfhi(x.x);
      dot += gqs[u*8+2]*bflo(x.y) + gqs[u*8+3]*bfhi(x.y);
      dot += gqs[u*8+4]*bflo(x.z) + gqs[u*8+5]*bfhi(x.z);
      dot += gqs[u*8+6]*bflo(x.w) + gqs[u*8+7]*bfhi(x.w);
    }
    sc[sl] = mask_at(maskp, flag, b_i * 4096 + s) ? -FLT_MAX : dot;
  }
  __syncthreads();
  float m = fmaxf(sc[t], sc[t + 256]);
  red[t] = m; __syncthreads();
  for (int st = 128; st > 0; st >>= 1){ if (t < st) red[t] = fmaxf(red[t], red[t + st]); __syncthreads(); }
  const float mc = red[0];
  __syncthreads();
  float ls = 0.f;
#pragma unroll
  for (int i = 0; i < 2; ++i){
    int sl = i * 256 + t;
    float p = __expf(sc[sl] - mc);
    sc[sl] = p; ls += p;
  }
  red[t] = ls; __syncthreads();
  for (int st = 128; st > 0; st >>= 1){ if (t < st) red[t] += red[t + st]; __syncthreads(); }
  const float lc = red[0];
  __syncthreads();
  const int dd = t & 63, part = t >> 6;
  float o = 0.f;
  for (int i2 = 0; i2 < 128; ++i2){
    int sl = part * 128 + i2;
    o += sc[sl] * bf2f(vb[((size_t)bh * 4096 + chunk * 512 + sl) * 64 + dd]);
  }
  red[t] = o; __syncthreads();
  float* gp = gp_out + ((size_t)bh * 8 + chunk) * 66;
  if (t == 0){ gp[0] = mc; gp[1] = lc; }
  if (t < 64) gp[2 + t] = red[t] + red[t+64] + red[t+128] + red[t+192];
}

__global__ __launch_bounds__(64) void greduce_kernel(const float* __restrict__ gp_in,
                                                     float* __restrict__ out){
  const int t = threadIdx.x, bh = blockIdx.x, b_i = bh / 12, h = bh % 12;
  const float* gp = gp_in + (size_t)bh * 8 * 66;
  float mg = -FLT_MAX;
#pragma unroll
  for (int c = 0; c < 8; ++c) mg = fmaxf(mg, gp[c * 66]);
  float lg = 0.f, o = 0.f;
#pragma unroll
  for (int c = 0; c < 8; ++c){
    float wv = __expf(gp[c * 66] - mg);
    lg += gp[c * 66 + 1] * wv;
    o  += gp[c * 66 + 2 + t] * wv;
  }
  out[(size_t)b_i * 768 + h * 64 + t] = o / lg;
}

// ---------------- launch ----------------
extern "C" void kernel_launch(void* const* d_in, const int* in_sizes, int n_in,
                              void* d_out, int out_size, void* d_ws, size_t ws_size,
                              hipStream_t stream) {
  const float* hid   = (const float*)d_in[0];
  const void*  maskp = d_in[1];
  const float* Wq  = (const float*)d_in[2];
  const float* Wk  = (const float*)d_in[3];
  const float* Wv  = (const float*)d_in[4];
  const float* Wgq = (const float*)d_in[5];
  const float* bq  = (const float*)d_in[6];
  const float* bk  = (const float*)d_in[7];
  const float* bv  = (const float*)d_in[8];
  const float* bgq = (const float*)d_in[9];
  float* out = (float*)d_out;

  char* wsb = (char*)d_ws;
  int* flag   = (int*)wsb;                       // 256 B
  u16* hb     = (u16*)(wsb + 256);               // 50331648 B
  u16* wT     = (u16*)(wsb + 50331904);          // 3538944 B
  u16* qb     = (u16*)(wsb + 53870848);          // 50331648 B
  u16* kb     = (u16*)(wsb + 104202496);         // 50331648 B
  u16* vb     = (u16*)(wsb + 154534144);         // 50331648 B
  u16* vtb    = (u16*)(wsb + 204865792);         // 50331648 B
  float* gq   = (float*)(wsb + 255197440);       // 24576 B
  float* gpart = (float*)(wsb + 255222016);      // 202752 B  (end ~255.4 MB)

  sniff_mask_kernel<<<1, 256, 0, stream>>>((const unsigned int*)maskp, flag);
  cvt_hidden_kernel<<<2048, 256, 0, stream>>>(hid, hb);
  cvt_wT_kernel<<<dim3(12, 12, 3), 256, 0, stream>>>(Wq, Wk, Wv, wT);
  proj_mfma_kernel<<<dim3(256, 18), 256, 0, stream>>>(hb, wT, bq, bk, bv, qb, kb, vb);
  vt_kernel<<<dim3(64, 96), 256, 0, stream>>>(vb, vtb);
  gq_kernel<<<96, 256, 0, stream>>>(hid, Wgq, bgq, gq);
  local_mfma_kernel<<<dim3(32, 96), 256, 0, stream>>>(qb, kb, vtb, maskp, flag, out);
  gpart_kernel<<<dim3(96, 8), 256, 0, stream>>>(gq, kb, vb, maskp, flag, gpart);
  greduce_kernel<<<96, 64, 0, stream>>>(gpart, out);
}